// Round 5
// baseline (198.594 us; speedup 1.0000x reference)
//
#include <hip/hip_runtime.h>
#include <math.h>

// Problem constants
#define Bb   2
#define Hh   64
#define Ww   160
#define DIMc 256
#define Nn   (Hh * Ww)                 // 10240 positions per batch
#define SCALEf 0.17677669529663687f    // 32^-0.5

typedef unsigned short u16;
typedef unsigned int   u32;
typedef __bf16 bf16x8 __attribute__((ext_vector_type(8)));
typedef float  f32x4  __attribute__((ext_vector_type(4)));

// fp32 -> bf16 round-to-nearest-even
__device__ __forceinline__ u16 f2bf(float f) {
    u32 u = __float_as_uint(f);
    u += 0x7fffu + ((u >> 16) & 1u);
    return (u16)(u >> 16);
}
__device__ __forceinline__ u32 pack2(float lo, float hi) {
    return (u32)f2bf(lo) | ((u32)f2bf(hi) << 16);
}
// packed bf16 pair -> floats (exact)
__device__ __forceinline__ float bflo(u32 u) { return __uint_as_float(u << 16); }
__device__ __forceinline__ float bfhi(u32 u) { return __uint_as_float(u & 0xffff0000u); }

// ---------------------------------------------------------------------------
// prep_w: all 4 weights to transposed bf16. Wt[wsel][n][k] = W[wsel][k][n].
// ---------------------------------------------------------------------------
__global__ __launch_bounds__(256) void prep_w(const float* __restrict__ Wq,
                                              const float* __restrict__ Wk,
                                              const float* __restrict__ Wv,
                                              const float* __restrict__ Wp,
                                              u16* __restrict__ WtAll)
{
    int id = blockIdx.x * 256 + threadIdx.x;     // 0 .. 262143
    int wsel = id >> 16;
    int rem  = id & 65535;
    int kk = rem >> 8, nn = rem & 255;
    const float* W = (wsel == 0) ? Wq : (wsel == 1) ? Wk : (wsel == 2) ? Wv : Wp;
    WtAll[(size_t)wsel * 65536 + nn * 256 + kk] = f2bf(W[kk * 256 + nn]);
}

// ---------------------------------------------------------------------------
// bf16 MFMA GEMM: C[64 x 256] block tile = A[64 x 256] @ Bt^T (Bt N-major).
// 256 threads = 4 waves side by side in n (64 cols each); wave = 4x4 grid of
// 16x16x32 MFMAs, acc[4][4] = 64 VGPR (proven no-spill). BK=32, 8 K-steps.
// A_IS_F32: A loaded as fp32 and converted to bf16 in-register (qkv path).
// ---------------------------------------------------------------------------
template <bool A_IS_F32, bool BF16OUT>
__device__ __forceinline__ void gemm_core64(const void* __restrict__ Avoid,
                                            const u16* __restrict__ Btg,
                                            u16* __restrict__ Cb,
                                            float* __restrict__ Cf,
                                            int m0)
{
    __shared__ u16 sA[64 * 32];    // 4 KB
    __shared__ u16 sB[256 * 32];   // 16 KB

    const int t    = threadIdx.x;
    const int lane = t & 63;
    const int wv   = t >> 6;       // wave's n-quarter (64 cols)
    const int col  = lane & 15;
    const int quad = lane >> 4;

    // A staging: thread t covers row r0 (0..63), 8 bf16 (16B) at kc0
    const int r0  = t >> 2;
    const int kc0 = (t & 3) * 8;

    f32x4 acc[4][4];
#pragma unroll
    for (int i = 0; i < 4; ++i)
#pragma unroll
        for (int j = 0; j < 4; ++j)
            acc[i][j] = (f32x4){0.f, 0.f, 0.f, 0.f};

    const float* Af = (const float*)Avoid;
    const u16*   Ab = (const u16*)Avoid;

    for (int k0 = 0; k0 < 256; k0 += 32) {
        uint4 areg;
        if (A_IS_F32) {
            const float* ap = Af + (size_t)(m0 + r0) * 256 + k0 + kc0;
            float4 a0 = *(const float4*)ap;
            float4 a1 = *(const float4*)(ap + 4);
            areg.x = pack2(a0.x, a0.y);
            areg.y = pack2(a0.z, a0.w);
            areg.z = pack2(a1.x, a1.y);
            areg.w = pack2(a1.z, a1.w);
        } else {
            areg = *(const uint4*)(Ab + (size_t)(m0 + r0) * 256 + k0 + kc0);
        }
        uint4 breg[4];
#pragma unroll
        for (int i = 0; i < 4; ++i) {
            int c = i * 256 + t, rB = c >> 2, kcB = (c & 3) * 8;
            breg[i] = *(const uint4*)(Btg + (size_t)rB * 256 + k0 + kcB);
        }
        __syncthreads();
        *(uint4*)(sA + r0 * 32 + kc0) = areg;
#pragma unroll
        for (int i = 0; i < 4; ++i) {
            int c = i * 256 + t, rB = c >> 2, kcB = (c & 3) * 8;
            *(uint4*)(sB + rB * 32 + kcB) = breg[i];
        }
        __syncthreads();

        bf16x8 af[4], bfr[4];
#pragma unroll
        for (int mt = 0; mt < 4; ++mt)
            af[mt] = *(const bf16x8*)(sA + (mt * 16 + col) * 32 + quad * 8);
#pragma unroll
        for (int nt = 0; nt < 4; ++nt)
            bfr[nt] = *(const bf16x8*)(sB + (wv * 64 + nt * 16 + col) * 32 + quad * 8);

#pragma unroll
        for (int mt = 0; mt < 4; ++mt)
#pragma unroll
            for (int nt = 0; nt < 4; ++nt)
                acc[mt][nt] = __builtin_amdgcn_mfma_f32_16x16x32_bf16(af[mt], bfr[nt], acc[mt][nt], 0, 0, 0);
    }

    // epilogue: C/D layout col=lane&15, row=quad*4+reg  (m89-verified)
#pragma unroll
    for (int mt = 0; mt < 4; ++mt) {
#pragma unroll
        for (int nt = 0; nt < 4; ++nt) {
            const int rowb = m0 + mt * 16 + quad * 4;
            const int colg = wv * 64 + nt * 16 + col;
#pragma unroll
            for (int rr = 0; rr < 4; ++rr) {
                float val = acc[mt][nt][rr];
                if (BF16OUT) Cb[(size_t)(rowb + rr) * 256 + colg] = f2bf(val);
                else         Cf[(size_t)(rowb + rr) * 256 + colg] = val;
            }
        }
    }
}

__global__ __launch_bounds__(256) void gemm_qkv(const float* __restrict__ x,
                                                const u16* __restrict__ WtAll,
                                                u16* __restrict__ q,
                                                u16* __restrict__ k,
                                                u16* __restrict__ v)
{
    const int z = blockIdx.y;
    u16* C = (z == 0) ? q : (z == 1) ? k : v;
    gemm_core64<true, true>(x, WtAll + (size_t)z * 65536, C, nullptr, blockIdx.x * 64);
}

__global__ __launch_bounds__(256) void gemm_proj(const u16* __restrict__ ao,
                                                 const u16* __restrict__ WtAll,
                                                 float* __restrict__ out)
{
    gemm_core64<false, false>(ao, WtAll + (size_t)3 * 65536, nullptr, out, blockIdx.x * 64);
}

// ---------------------------------------------------------------------------
// Attention: ONE WAVE per position. No LDS, no __syncthreads.
// ---------------------------------------------------------------------------
__global__ __launch_bounds__(256) void attn_kernel(const u16* __restrict__ q,
                                                   const u16* __restrict__ k,
                                                   const u16* __restrict__ v,
                                                   const float* __restrict__ moff,
                                                   u16* __restrict__ ao)
{
    const int wv   = threadIdx.x >> 6;
    const int lane = threadIdx.x & 63;
    const int pos  = blockIdx.x * 4 + wv;
    const int rowbase = (pos >= Nn) ? Nn : 0;

    float2 mo = *(const float2*)(moff + (size_t)pos * 2);
    float ox = fminf(fmaxf(mo.x, 1.0f), (float)(Ww - 2) - 0.001f);
    float oy = fminf(fmaxf(mo.y, 1.0f), (float)(Hh - 2) - 0.001f);
    float mxf = floorf(ox), myf = floorf(oy);
    float fx = ox - mxf, fy = oy - myf;
    int imx = (int)mxf, imy = (int)myf;

    const int h  = lane & 7;
    const int a0 = lane >> 3;

    uint4 q4[4];
    {
        const uint4* qp = (const uint4*)(q + (size_t)pos * 256 + h * 32);
#pragma unroll
        for (int jj = 0; jj < 4; ++jj) q4[jj] = qp[jj];
    }

    float s[2];
#pragma unroll
    for (int p = 0; p < 2; ++p) {
        int a   = a0 + 8 * p;
        int row = rowbase + (imy + (a >> 2) - 1) * Ww + imx + (a & 3) - 1;
        const uint4* kp = (const uint4*)(k + (size_t)row * 256 + h * 32);
        float acc = 0.f;
#pragma unroll
        for (int jj = 0; jj < 4; ++jj) {
            uint4 kw = kp[jj];
            acc += bflo(q4[jj].x) * bflo(kw.x) + bfhi(q4[jj].x) * bfhi(kw.x)
                 + bflo(q4[jj].y) * bflo(kw.y) + bfhi(q4[jj].y) * bfhi(kw.y)
                 + bflo(q4[jj].z) * bflo(kw.z) + bfhi(q4[jj].z) * bfhi(kw.z)
                 + bflo(q4[jj].w) * bflo(kw.w) + bfhi(q4[jj].w) * bfhi(kw.w);
        }
        s[p] = acc * SCALEf;
    }

    auto wc = [](int r, float f) { return r == 0 ? 1.f - f : (r == 3 ? f : 1.f); };
    float bw0 = wc(a0 >> 2, fy) * wc(a0 & 3, fx);
    float bw1 = wc((a0 + 8) >> 2, fy) * wc(a0 & 3, fx);

    float m = fmaxf(s[0], s[1]);
    m = fmaxf(m, __shfl_xor(m, 8));
    m = fmaxf(m, __shfl_xor(m, 16));
    m = fmaxf(m, __shfl_xor(m, 32));
    float e0 = expf(s[0] - m) * bw0;
    float e1 = expf(s[1] - m) * bw1;
    float sum = e0 + e1;
    sum += __shfl_xor(sum, 8);
    sum += __shfl_xor(sum, 16);
    sum += __shfl_xor(sum, 32);
    float inv = 1.f / sum;
    float p0 = e0 * inv, p1 = e1 * inv;

    float acc0 = 0.f, acc1 = 0.f, acc2 = 0.f, acc3 = 0.f;
    const int myh = lane >> 3;
#pragma unroll
    for (int a = 0; a < 16; ++a) {
        int row = rowbase + (imy + (a >> 2) - 1) * Ww + imx + (a & 3) - 1;
        uint2 vw = *(const uint2*)(v + (size_t)row * 256 + 4 * lane);
        int src = ((a & 7) << 3) | myh;
        float pa = __shfl(a < 8 ? p0 : p1, src);
        acc0 += pa * bflo(vw.x); acc1 += pa * bfhi(vw.x);
        acc2 += pa * bflo(vw.y); acc3 += pa * bfhi(vw.y);
    }
    uint2 o;
    o.x = pack2(acc0, acc1);
    o.y = pack2(acc2, acc3);
    *(uint2*)(ao + (size_t)pos * 256 + 4 * lane) = o;
}

// ---------------------------------------------------------------------------
extern "C" void kernel_launch(void* const* d_in, const int* in_sizes, int n_in,
                              void* d_out, int out_size, void* d_ws, size_t ws_size,
                              hipStream_t stream)
{
    const float* x     = (const float*)d_in[0];
    const float* moff  = (const float*)d_in[1];
    const float* Wq    = (const float*)d_in[2];
    const float* Wk    = (const float*)d_in[3];
    const float* Wv    = (const float*)d_in[4];
    const float* Wproj = (const float*)d_in[5];
    float* out = (float*)d_out;

    const size_t NTOT = (size_t)Bb * Nn * DIMc;   // 5,242,880
    u16* ws    = (u16*)d_ws;
    u16* WtAll = ws;
    u16* q     = WtAll + 4 * 65536;
    u16* k     = q + NTOT;
    u16* v     = k + NTOT;
    u16* ao    = v + NTOT;

    prep_w<<<dim3(1024), dim3(256), 0, stream>>>(Wq, Wk, Wv, Wproj, WtAll);
    gemm_qkv<<<dim3(320, 3), dim3(256), 0, stream>>>(x, WtAll, q, k, v);
    attn_kernel<<<dim3(Bb * Nn / 4), dim3(256), 0, stream>>>(q, k, v, moff, ao);
    gemm_proj<<<dim3(320), dim3(256), 0, stream>>>(ao, WtAll, out);
}

// Round 6
// 170.384 us; speedup vs baseline: 1.1656x; 1.1656x over previous
//
#include <hip/hip_runtime.h>
#include <math.h>

// Problem constants
#define Bb   2
#define Hh   64
#define Ww   160
#define DIMc 256
#define Nn   (Hh * Ww)                 // 10240 positions per batch
#define SCALEf 0.17677669529663687f    // 32^-0.5

typedef unsigned short u16;
typedef unsigned int   u32;
typedef __bf16 bf16x8 __attribute__((ext_vector_type(8)));
typedef float  f32x4  __attribute__((ext_vector_type(4)));

// fp32 -> bf16 round-to-nearest-even
__device__ __forceinline__ u16 f2bf(float f) {
    u32 u = __float_as_uint(f);
    u += 0x7fffu + ((u >> 16) & 1u);
    return (u16)(u >> 16);
}
__device__ __forceinline__ u32 pack2(float lo, float hi) {
    return (u32)f2bf(lo) | ((u32)f2bf(hi) << 16);
}
// packed bf16 pair -> floats (exact)
__device__ __forceinline__ float bflo(u32 u) { return __uint_as_float(u << 16); }
__device__ __forceinline__ float bfhi(u32 u) { return __uint_as_float(u & 0xffff0000u); }

__device__ __forceinline__ bf16x8 as_bf8(uint4 u) {
    union { uint4 u; bf16x8 b; } c; c.u = u; return c.b;
}

// ---------------------------------------------------------------------------
// prep: convert x to bf16 (blocks 0..5119) and all 4 weights to transposed
// bf16 (blocks 5120..6143). Wt[wsel][n][k] = W[wsel][k][n].
// ---------------------------------------------------------------------------
__global__ __launch_bounds__(256) void prep(const float* __restrict__ x,
                                            const float* __restrict__ Wq,
                                            const float* __restrict__ Wk,
                                            const float* __restrict__ Wv,
                                            const float* __restrict__ Wp,
                                            u16* __restrict__ xb,
                                            u16* __restrict__ WtAll)
{
    const int bid = blockIdx.x;
    if (bid < 5120) {
        size_t id = (size_t)bid * 256 + threadIdx.x;   // one float4 per thread
        float4 vv = *(const float4*)(x + id * 4);
        ushort4 ov = make_ushort4(f2bf(vv.x), f2bf(vv.y), f2bf(vv.z), f2bf(vv.w));
        *(ushort4*)(xb + id * 4) = ov;
    } else {
        int id = (bid - 5120) * 256 + threadIdx.x;     // 0 .. 262143
        int wsel = id >> 16;
        int rem  = id & 65535;
        int kk = rem >> 8, nn = rem & 255;
        const float* W = (wsel == 0) ? Wq : (wsel == 1) ? Wk : (wsel == 2) ? Wv : Wp;
        WtAll[(size_t)wsel * 65536 + nn * 256 + kk] = f2bf(W[kk * 256 + nn]);
    }
}

// ---------------------------------------------------------------------------
// Weight-stationary bf16 MFMA GEMM for K=256, N=256.
// Block = 256 threads = 4 waves; wave wv owns n-strip [wv*64, wv*64+64) and
// holds its FULL B-strip (64 x 256) in 128 VGPRs, loaded once in MFMA
// fragment layout. Main loop: direct global A-fragment loads + MFMA only —
// NO LDS, NO barriers. Block computes a 64(m) x 256(n) output tile.
// bf16 epilogue staged via LDS -> coalesced dwordx4 stores.
// ---------------------------------------------------------------------------
template <bool BF16OUT>
__device__ __forceinline__ void gemm_ws(const u16* __restrict__ Ag,
                                        const u16* __restrict__ Btg,
                                        u16* __restrict__ Cb,
                                        float* __restrict__ Cf,
                                        int m0)
{
    const int t    = threadIdx.x;
    const int lane = t & 63;
    const int wv   = t >> 6;
    const int col  = lane & 15;
    const int quad = lane >> 4;
    const int nb   = wv * 64;

    // B-strip resident in registers: breg[nt][kf], fragment layout
    // (lane -> n = nb + nt*16 + col, k = kf*32 + quad*8 .. +8)
    uint4 breg[4][8];
#pragma unroll
    for (int nt = 0; nt < 4; ++nt)
#pragma unroll
        for (int kf = 0; kf < 8; ++kf)
            breg[nt][kf] = *(const uint4*)(Btg + (size_t)(nb + nt * 16 + col) * 256 + kf * 32 + quad * 8);

    f32x4 acc[4][4];
#pragma unroll
    for (int i = 0; i < 4; ++i)
#pragma unroll
        for (int j = 0; j < 4; ++j)
            acc[i][j] = (f32x4){0.f, 0.f, 0.f, 0.f};

    const u16* Abase = Ag + (size_t)m0 * 256;

#pragma unroll
    for (int kf = 0; kf < 8; ++kf) {
        uint4 areg[4];
#pragma unroll
        for (int mt = 0; mt < 4; ++mt)
            areg[mt] = *(const uint4*)(Abase + (size_t)(mt * 16 + col) * 256 + kf * 32 + quad * 8);
#pragma unroll
        for (int mt = 0; mt < 4; ++mt)
#pragma unroll
            for (int nt = 0; nt < 4; ++nt)
                acc[mt][nt] = __builtin_amdgcn_mfma_f32_16x16x32_bf16(
                    as_bf8(areg[mt]), as_bf8(breg[nt][kf]), acc[mt][nt], 0, 0, 0);
    }

    // epilogue: C/D layout col=lane&15 (n), row=quad*4+reg (m)
    if constexpr (BF16OUT) {
        __shared__ u16 sC[64 * 256];   // 32 KB
#pragma unroll
        for (int mt = 0; mt < 4; ++mt)
#pragma unroll
            for (int nt = 0; nt < 4; ++nt)
#pragma unroll
                for (int rr = 0; rr < 4; ++rr)
                    sC[(mt * 16 + quad * 4 + rr) * 256 + nb + nt * 16 + col] = f2bf(acc[mt][nt][rr]);
        __syncthreads();
        // 2048 16B chunks, 8 per thread, fully coalesced
#pragma unroll
        for (int i = 0; i < 8; ++i) {
            int j   = i * 256 + t;
            int row = j >> 5;
            int off = (j & 31) * 8;
            *(uint4*)(Cb + (size_t)(m0 + row) * 256 + off) = *(const uint4*)(sC + row * 256 + off);
        }
    } else {
#pragma unroll
        for (int mt = 0; mt < 4; ++mt)
#pragma unroll
            for (int nt = 0; nt < 4; ++nt) {
                const int rowb = m0 + mt * 16 + quad * 4;
                const int colg = nb + nt * 16 + col;
#pragma unroll
                for (int rr = 0; rr < 4; ++rr)
                    Cf[(size_t)(rowb + rr) * 256 + colg] = acc[mt][nt][rr];
            }
    }
}

__global__ __launch_bounds__(256, 2) void gemm_qkv(const u16* __restrict__ xb,
                                                   const u16* __restrict__ WtAll,
                                                   u16* __restrict__ q,
                                                   u16* __restrict__ k,
                                                   u16* __restrict__ v)
{
    const int z = blockIdx.x;          // z fastest: 3 consecutive blocks share A rows
    u16* C = (z == 0) ? q : (z == 1) ? k : v;
    gemm_ws<true>(xb, WtAll + (size_t)z * 65536, C, nullptr, blockIdx.y * 64);
}

__global__ __launch_bounds__(256, 2) void gemm_proj(const u16* __restrict__ ao,
                                                    const u16* __restrict__ WtAll,
                                                    float* __restrict__ out)
{
    gemm_ws<false>(ao, WtAll + (size_t)3 * 65536, nullptr, out, blockIdx.x * 64);
}

// ---------------------------------------------------------------------------
// Attention: ONE WAVE per position. No LDS, no __syncthreads.
// ---------------------------------------------------------------------------
__global__ __launch_bounds__(256) void attn_kernel(const u16* __restrict__ q,
                                                   const u16* __restrict__ k,
                                                   const u16* __restrict__ v,
                                                   const float* __restrict__ moff,
                                                   u16* __restrict__ ao)
{
    const int wv   = threadIdx.x >> 6;
    const int lane = threadIdx.x & 63;
    const int pos  = blockIdx.x * 4 + wv;
    const int rowbase = (pos >= Nn) ? Nn : 0;

    float2 mo = *(const float2*)(moff + (size_t)pos * 2);
    float ox = fminf(fmaxf(mo.x, 1.0f), (float)(Ww - 2) - 0.001f);
    float oy = fminf(fmaxf(mo.y, 1.0f), (float)(Hh - 2) - 0.001f);
    float mxf = floorf(ox), myf = floorf(oy);
    float fx = ox - mxf, fy = oy - myf;
    int imx = (int)mxf, imy = (int)myf;

    const int h  = lane & 7;
    const int a0 = lane >> 3;

    uint4 q4[4];
    {
        const uint4* qp = (const uint4*)(q + (size_t)pos * 256 + h * 32);
#pragma unroll
        for (int jj = 0; jj < 4; ++jj) q4[jj] = qp[jj];
    }

    float s[2];
#pragma unroll
    for (int p = 0; p < 2; ++p) {
        int a   = a0 + 8 * p;
        int row = rowbase + (imy + (a >> 2) - 1) * Ww + imx + (a & 3) - 1;
        const uint4* kp = (const uint4*)(k + (size_t)row * 256 + h * 32);
        float acc = 0.f;
#pragma unroll
        for (int jj = 0; jj < 4; ++jj) {
            uint4 kw = kp[jj];
            acc += bflo(q4[jj].x) * bflo(kw.x) + bfhi(q4[jj].x) * bfhi(kw.x)
                 + bflo(q4[jj].y) * bflo(kw.y) + bfhi(q4[jj].y) * bfhi(kw.y)
                 + bflo(q4[jj].z) * bflo(kw.z) + bfhi(q4[jj].z) * bfhi(kw.z)
                 + bflo(q4[jj].w) * bflo(kw.w) + bfhi(q4[jj].w) * bfhi(kw.w);
        }
        s[p] = acc * SCALEf;
    }

    auto wc = [](int r, float f) { return r == 0 ? 1.f - f : (r == 3 ? f : 1.f); };
    float bw0 = wc(a0 >> 2, fy) * wc(a0 & 3, fx);
    float bw1 = wc((a0 + 8) >> 2, fy) * wc(a0 & 3, fx);

    float m = fmaxf(s[0], s[1]);
    m = fmaxf(m, __shfl_xor(m, 8));
    m = fmaxf(m, __shfl_xor(m, 16));
    m = fmaxf(m, __shfl_xor(m, 32));
    float e0 = expf(s[0] - m) * bw0;
    float e1 = expf(s[1] - m) * bw1;
    float sum = e0 + e1;
    sum += __shfl_xor(sum, 8);
    sum += __shfl_xor(sum, 16);
    sum += __shfl_xor(sum, 32);
    float inv = 1.f / sum;
    float p0 = e0 * inv, p1 = e1 * inv;

    float acc0 = 0.f, acc1 = 0.f, acc2 = 0.f, acc3 = 0.f;
    const int myh = lane >> 3;
#pragma unroll
    for (int a = 0; a < 16; ++a) {
        int row = rowbase + (imy + (a >> 2) - 1) * Ww + imx + (a & 3) - 1;
        uint2 vw = *(const uint2*)(v + (size_t)row * 256 + 4 * lane);
        int src = ((a & 7) << 3) | myh;
        float pa = __shfl(a < 8 ? p0 : p1, src);
        acc0 += pa * bflo(vw.x); acc1 += pa * bfhi(vw.x);
        acc2 += pa * bflo(vw.y); acc3 += pa * bfhi(vw.y);
    }
    uint2 o;
    o.x = pack2(acc0, acc1);
    o.y = pack2(acc2, acc3);
    *(uint2*)(ao + (size_t)pos * 256 + 4 * lane) = o;
}

// ---------------------------------------------------------------------------
extern "C" void kernel_launch(void* const* d_in, const int* in_sizes, int n_in,
                              void* d_out, int out_size, void* d_ws, size_t ws_size,
                              hipStream_t stream)
{
    const float* x     = (const float*)d_in[0];
    const float* moff  = (const float*)d_in[1];
    const float* Wq    = (const float*)d_in[2];
    const float* Wk    = (const float*)d_in[3];
    const float* Wv    = (const float*)d_in[4];
    const float* Wproj = (const float*)d_in[5];
    float* out = (float*)d_out;

    const size_t NTOT = (size_t)Bb * Nn * DIMc;   // 5,242,880
    u16* ws    = (u16*)d_ws;
    u16* xb    = ws;
    u16* WtAll = xb + NTOT;
    u16* q     = WtAll + 4 * 65536;
    u16* k     = q + NTOT;
    u16* v     = k + NTOT;
    u16* ao    = v + NTOT;

    prep<<<dim3(6144), dim3(256), 0, stream>>>(x, Wq, Wk, Wv, Wproj, xb, WtAll);
    gemm_qkv<<<dim3(3, 320), dim3(256), 0, stream>>>(xb, WtAll, q, k, v);
    attn_kernel<<<dim3(Bb * Nn / 4), dim3(256), 0, stream>>>(q, k, v, moff, ao);
    gemm_proj<<<dim3(320), dim3(256), 0, stream>>>(ao, WtAll, out);
}

// Round 7
// 143.396 us; speedup vs baseline: 1.3849x; 1.1882x over previous
//
#include <hip/hip_runtime.h>
#include <math.h>

// Problem constants
#define Bb   2
#define Hh   64
#define Ww   160
#define DIMc 256
#define Nn   (Hh * Ww)                 // 10240 positions per batch
#define SCALEf 0.17677669529663687f    // 32^-0.5

typedef unsigned short u16;
typedef unsigned int   u32;
typedef __bf16 bf16x8 __attribute__((ext_vector_type(8)));
typedef float  f32x4  __attribute__((ext_vector_type(4)));

// fp32 -> bf16 round-to-nearest-even
__device__ __forceinline__ u16 f2bf(float f) {
    u32 u = __float_as_uint(f);
    u += 0x7fffu + ((u >> 16) & 1u);
    return (u16)(u >> 16);
}
__device__ __forceinline__ u32 pack2(float lo, float hi) {
    return (u32)f2bf(lo) | ((u32)f2bf(hi) << 16);
}
// packed bf16 pair -> floats (exact)
__device__ __forceinline__ float bflo(u32 u) { return __uint_as_float(u << 16); }
__device__ __forceinline__ float bfhi(u32 u) { return __uint_as_float(u & 0xffff0000u); }

// ---------------------------------------------------------------------------
// prep_w: all 4 weights to transposed bf16. Wt[wsel][n][k] = W[wsel][k][n].
// ---------------------------------------------------------------------------
__global__ __launch_bounds__(256) void prep_w(const float* __restrict__ Wq,
                                              const float* __restrict__ Wk,
                                              const float* __restrict__ Wv,
                                              const float* __restrict__ Wp,
                                              u16* __restrict__ WtAll)
{
    int id = blockIdx.x * 256 + threadIdx.x;     // 0 .. 262143
    int wsel = id >> 16;
    int rem  = id & 65535;
    int kk = rem >> 8, nn = rem & 255;
    const float* W = (wsel == 0) ? Wq : (wsel == 1) ? Wk : (wsel == 2) ? Wv : Wp;
    WtAll[(size_t)wsel * 65536 + nn * 256 + kk] = f2bf(W[kk * 256 + nn]);
}

// ---------------------------------------------------------------------------
// bf16 MFMA GEMM (R4-proven 128x128 core): C = A[Mx256] @ Bt^T (Bt N-major).
// 256 threads = 4 waves in 2x2; wave = 4x4 grid of 16x16x32 MFMAs,
// acc[4][4] = 64 VGPR (no spill). BK=32, 8 K-steps.
// A_IS_F32: A loaded fp32 + packed to bf16 in-register during staging.
// Epilogue: C staged through the (reused) 32 KB LDS -> coalesced 16B stores.
// ---------------------------------------------------------------------------
template <bool A_IS_F32, bool BF16OUT>
__device__ __forceinline__ void gemm_core(const void* __restrict__ Avoid,
                                          const u16* __restrict__ Btg,
                                          u16* __restrict__ Cb,
                                          float* __restrict__ Cf)
{
    __shared__ __align__(16) char smem[32768];
    u16* sA = (u16*)smem;             //  8 KB: 128 rows x 32 k
    u16* sB = (u16*)(smem + 8192);    //  8 KB: 128 cols x 32 k

    const int t    = threadIdx.x;
    const int lane = t & 63;
    const int wv   = t >> 6;
    const int wm   = wv & 1;      // wave m-half
    const int wn   = wv >> 1;     // wave n-half
    const int m0   = blockIdx.y * 128;
    const int n0   = blockIdx.x * 128;

    // staging: thread t covers rows r0 and r0+64, 8 bf16 (16B) each
    const int r0  = t >> 2;
    const int kc0 = (t & 3) * 8;

    const int col  = lane & 15;
    const int quad = lane >> 4;

    f32x4 acc[4][4];
#pragma unroll
    for (int i = 0; i < 4; ++i)
#pragma unroll
        for (int j = 0; j < 4; ++j)
            acc[i][j] = (f32x4){0.f, 0.f, 0.f, 0.f};

    const float* Af = (const float*)Avoid;
    const u16*   Ab = (const u16*)Avoid;
    const u16*   Bbase = Btg + (size_t)n0 * 256;

    for (int k0 = 0; k0 < 256; k0 += 32) {
        uint4 a0, a1;
        if (A_IS_F32) {
            const float* ap0 = Af + (size_t)(m0 + r0) * 256 + k0 + kc0;
            const float* ap1 = Af + (size_t)(m0 + 64 + r0) * 256 + k0 + kc0;
            float4 f0 = *(const float4*)ap0, f1 = *(const float4*)(ap0 + 4);
            float4 f2 = *(const float4*)ap1, f3 = *(const float4*)(ap1 + 4);
            a0.x = pack2(f0.x, f0.y); a0.y = pack2(f0.z, f0.w);
            a0.z = pack2(f1.x, f1.y); a0.w = pack2(f1.z, f1.w);
            a1.x = pack2(f2.x, f2.y); a1.y = pack2(f2.z, f2.w);
            a1.z = pack2(f3.x, f3.y); a1.w = pack2(f3.z, f3.w);
        } else {
            a0 = *(const uint4*)(Ab + (size_t)(m0 + r0) * 256 + k0 + kc0);
            a1 = *(const uint4*)(Ab + (size_t)(m0 + 64 + r0) * 256 + k0 + kc0);
        }
        uint4 b0 = *(const uint4*)(Bbase + (size_t)r0 * 256 + k0 + kc0);
        uint4 b1 = *(const uint4*)(Bbase + (size_t)(64 + r0) * 256 + k0 + kc0);
        __syncthreads();
        *(uint4*)(sA + r0 * 32 + kc0)        = a0;
        *(uint4*)(sA + (64 + r0) * 32 + kc0) = a1;
        *(uint4*)(sB + r0 * 32 + kc0)        = b0;
        *(uint4*)(sB + (64 + r0) * 32 + kc0) = b1;
        __syncthreads();

        bf16x8 af[4], bfr[4];
#pragma unroll
        for (int mt = 0; mt < 4; ++mt)
            af[mt] = *(const bf16x8*)(sA + (wm * 64 + mt * 16 + col) * 32 + quad * 8);
#pragma unroll
        for (int nt = 0; nt < 4; ++nt)
            bfr[nt] = *(const bf16x8*)(sB + (wn * 64 + nt * 16 + col) * 32 + quad * 8);

#pragma unroll
        for (int mt = 0; mt < 4; ++mt)
#pragma unroll
            for (int nt = 0; nt < 4; ++nt)
                acc[mt][nt] = __builtin_amdgcn_mfma_f32_16x16x32_bf16(af[mt], bfr[nt], acc[mt][nt], 0, 0, 0);
    }

    // Epilogue. C/D layout: col=lane&15 (n), row=quad*4+reg (m). Stage via
    // LDS (reusing sA/sB space) for coalesced global stores.
    __syncthreads();   // last iteration's ds_reads complete before overwrite
    if (BF16OUT) {
        u16* sC = (u16*)smem;             // 128 x 128 bf16 = 32 KB
#pragma unroll
        for (int mt = 0; mt < 4; ++mt)
#pragma unroll
            for (int nt = 0; nt < 4; ++nt) {
                const int rw = wm * 64 + mt * 16 + quad * 4;
                const int cl = wn * 64 + nt * 16 + col;
#pragma unroll
                for (int rr = 0; rr < 4; ++rr)
                    sC[(rw + rr) * 128 + cl] = f2bf(acc[mt][nt][rr]);
            }
        __syncthreads();
        // 128 rows x 128 cols x 2B = 2048 16B chunks; 8 per thread, coalesced
#pragma unroll
        for (int i = 0; i < 8; ++i) {
            int j   = i * 256 + t;
            int row = j >> 4;
            int off = (j & 15) * 8;
            *(uint4*)(Cb + (size_t)(m0 + row) * 256 + n0 + off) = *(const uint4*)(sC + row * 128 + off);
        }
    } else {
        float* sC = (float*)smem;         // 64 x 128 fp32 = 32 KB per pass
#pragma unroll
        for (int ph = 0; ph < 2; ++ph) {
            if (wm == ph) {
#pragma unroll
                for (int mt = 0; mt < 4; ++mt)
#pragma unroll
                    for (int nt = 0; nt < 4; ++nt) {
                        const int rw = mt * 16 + quad * 4;
                        const int cl = wn * 64 + nt * 16 + col;
#pragma unroll
                        for (int rr = 0; rr < 4; ++rr)
                            sC[(rw + rr) * 128 + cl] = acc[mt][nt][rr];
                    }
            }
            __syncthreads();
            // 64 rows x 128 f32 = 2048 16B chunks; 8 per thread, coalesced
#pragma unroll
            for (int i = 0; i < 8; ++i) {
                int j   = i * 256 + t;
                int row = j >> 5;
                int off = (j & 31) * 4;
                *(float4*)(Cf + (size_t)(m0 + ph * 64 + row) * 256 + n0 + off) =
                    *(const float4*)(sC + row * 128 + off);
            }
            __syncthreads();
        }
    }
}

__global__ __launch_bounds__(256) void gemm_qkv(const float* __restrict__ x,
                                                const u16* __restrict__ WtAll,
                                                u16* __restrict__ q,
                                                u16* __restrict__ k,
                                                u16* __restrict__ v)
{
    const int z = blockIdx.z;
    u16* C = (z == 0) ? q : (z == 1) ? k : v;
    gemm_core<true, true>(x, WtAll + (size_t)z * 65536, C, nullptr);
}

__global__ __launch_bounds__(256) void gemm_proj(const u16* __restrict__ ao,
                                                 const u16* __restrict__ WtAll,
                                                 float* __restrict__ out)
{
    gemm_core<false, false>(ao, WtAll + (size_t)3 * 65536, nullptr, out);
}

// ---------------------------------------------------------------------------
// Attention: ONE WAVE per position. No LDS, no __syncthreads. (R4-proven)
// ---------------------------------------------------------------------------
__global__ __launch_bounds__(256) void attn_kernel(const u16* __restrict__ q,
                                                   const u16* __restrict__ k,
                                                   const u16* __restrict__ v,
                                                   const float* __restrict__ moff,
                                                   u16* __restrict__ ao)
{
    const int wv   = threadIdx.x >> 6;
    const int lane = threadIdx.x & 63;
    const int pos  = blockIdx.x * 4 + wv;
    const int rowbase = (pos >= Nn) ? Nn : 0;

    float2 mo = *(const float2*)(moff + (size_t)pos * 2);
    float ox = fminf(fmaxf(mo.x, 1.0f), (float)(Ww - 2) - 0.001f);
    float oy = fminf(fmaxf(mo.y, 1.0f), (float)(Hh - 2) - 0.001f);
    float mxf = floorf(ox), myf = floorf(oy);
    float fx = ox - mxf, fy = oy - myf;
    int imx = (int)mxf, imy = (int)myf;

    const int h  = lane & 7;
    const int a0 = lane >> 3;

    uint4 q4[4];
    {
        const uint4* qp = (const uint4*)(q + (size_t)pos * 256 + h * 32);
#pragma unroll
        for (int jj = 0; jj < 4; ++jj) q4[jj] = qp[jj];
    }

    float s[2];
#pragma unroll
    for (int p = 0; p < 2; ++p) {
        int a   = a0 + 8 * p;
        int row = rowbase + (imy + (a >> 2) - 1) * Ww + imx + (a & 3) - 1;
        const uint4* kp = (const uint4*)(k + (size_t)row * 256 + h * 32);
        float acc = 0.f;
#pragma unroll
        for (int jj = 0; jj < 4; ++jj) {
            uint4 kw = kp[jj];
            acc += bflo(q4[jj].x) * bflo(kw.x) + bfhi(q4[jj].x) * bfhi(kw.x)
                 + bflo(q4[jj].y) * bflo(kw.y) + bfhi(q4[jj].y) * bfhi(kw.y)
                 + bflo(q4[jj].z) * bflo(kw.z) + bfhi(q4[jj].z) * bfhi(kw.z)
                 + bflo(q4[jj].w) * bflo(kw.w) + bfhi(q4[jj].w) * bfhi(kw.w);
        }
        s[p] = acc * SCALEf;
    }

    auto wc = [](int r, float f) { return r == 0 ? 1.f - f : (r == 3 ? f : 1.f); };
    float bw0 = wc(a0 >> 2, fy) * wc(a0 & 3, fx);
    float bw1 = wc((a0 + 8) >> 2, fy) * wc(a0 & 3, fx);

    float m = fmaxf(s[0], s[1]);
    m = fmaxf(m, __shfl_xor(m, 8));
    m = fmaxf(m, __shfl_xor(m, 16));
    m = fmaxf(m, __shfl_xor(m, 32));
    float e0 = expf(s[0] - m) * bw0;
    float e1 = expf(s[1] - m) * bw1;
    float sum = e0 + e1;
    sum += __shfl_xor(sum, 8);
    sum += __shfl_xor(sum, 16);
    sum += __shfl_xor(sum, 32);
    float inv = 1.f / sum;
    float p0 = e0 * inv, p1 = e1 * inv;

    float acc0 = 0.f, acc1 = 0.f, acc2 = 0.f, acc3 = 0.f;
    const int myh = lane >> 3;
#pragma unroll
    for (int a = 0; a < 16; ++a) {
        int row = rowbase + (imy + (a >> 2) - 1) * Ww + imx + (a & 3) - 1;
        uint2 vw = *(const uint2*)(v + (size_t)row * 256 + 4 * lane);
        int src = ((a & 7) << 3) | myh;
        float pa = __shfl(a < 8 ? p0 : p1, src);
        acc0 += pa * bflo(vw.x); acc1 += pa * bfhi(vw.x);
        acc2 += pa * bflo(vw.y); acc3 += pa * bfhi(vw.y);
    }
    uint2 o;
    o.x = pack2(acc0, acc1);
    o.y = pack2(acc2, acc3);
    *(uint2*)(ao + (size_t)pos * 256 + 4 * lane) = o;
}

// ---------------------------------------------------------------------------
extern "C" void kernel_launch(void* const* d_in, const int* in_sizes, int n_in,
                              void* d_out, int out_size, void* d_ws, size_t ws_size,
                              hipStream_t stream)
{
    const float* x     = (const float*)d_in[0];
    const float* moff  = (const float*)d_in[1];
    const float* Wq    = (const float*)d_in[2];
    const float* Wk    = (const float*)d_in[3];
    const float* Wv    = (const float*)d_in[4];
    const float* Wproj = (const float*)d_in[5];
    float* out = (float*)d_out;

    const size_t NTOT = (size_t)Bb * Nn * DIMc;   // 5,242,880
    u16* ws    = (u16*)d_ws;
    u16* WtAll = ws;
    u16* q     = WtAll + 4 * 65536;
    u16* k     = q + NTOT;
    u16* v     = k + NTOT;
    u16* ao    = v + NTOT;

    prep_w<<<dim3(1024), dim3(256), 0, stream>>>(Wq, Wk, Wv, Wproj, WtAll);
    gemm_qkv<<<dim3(2, 160, 3), dim3(256), 0, stream>>>(x, WtAll, q, k, v);
    attn_kernel<<<dim3(Bb * Nn / 4), dim3(256), 0, stream>>>(q, k, v, moff, ao);
    gemm_proj<<<dim3(2, 160, 1), dim3(256), 0, stream>>>(ao, WtAll, out);
}